// Round 11
// baseline (414.684 us; speedup 1.0000x reference)
//
#include <hip/hip_runtime.h>
#include <math.h>

#define Nn 10000
#define Ee 160000
#define NBb 8
#define Gg 100
#define CSRMAX 230400            // >= Ee + 7*Nn, multiple of 256
#define NBATCH (CSRMAX / 8)      // 28800

// sh record per slot: [0..3]=sh0..3, [4..7]=sh4..7, [8]=sh8, [9]=src bits, [10,11]=0
__device__ __align__(16) float g_shc[(size_t)CSRMAX * 12];
__device__ __align__(16) float g_R[(size_t)CSRMAX * 64];    // [slot][64]
__device__ __align__(16) float g_P[(size_t)NBATCH * 576];   // per-batch partial A [9][64]
__device__ float g_h[2][Nn * 64];
__device__ float g_h1[Nn * 64];
__device__ float g_hsc[Nn * 64];
__device__ float g_nodeE[2][Nn];   // per-layer node energies (no atomics)
__device__ float g_wpro[64];       // W_prod[1] @ w_ro[1]
__device__ int   g_deg[Nn];
__device__ int   g_offs[Nn + 1];
__device__ int   g_cursor[Nn];
__device__ int2  g_er[CSRMAX];     // per-slot (sender, receiver); .x=-1 for pads
__device__ float g_W1T[64 * NBb];  // W_r1 transposed: [j][k]

__global__ __launch_bounds__(256) void k_zero(float* out, int out_size) {
    int i = blockIdx.x * 256 + threadIdx.x;
    if (i < CSRMAX) g_er[i].x = -1;
    if (i < out_size) out[i] = 0.0f;
    if (i < Nn) { g_deg[i] = 0; g_cursor[i] = 0; }
}

// degree count; block 0 also transposes W_r1 and computes W_prod[1]@w_ro[1]
__global__ __launch_bounds__(256) void k_deg(const int* __restrict__ eidx,
                                             const float* __restrict__ Wr1,
                                             const float* __restrict__ Wprod1,
                                             const float* __restrict__ wro1) {
    int e = blockIdx.x * 256 + threadIdx.x;
    if (e < Ee) atomicAdd(&g_deg[eidx[Ee + e]], 1);
    if (blockIdx.x == 0) {
        for (int i = threadIdx.x; i < 64 * NBb; i += 256) {
            int k = i >> 6, j = i & 63;  // Wr1[k][j]
            g_W1T[j * NBb + k] = Wr1[i];
        }
        if (threadIdx.x < 64) {
            int k = threadIdx.x;
            float s = 0.0f;
#pragma unroll
            for (int c = 0; c < 64; c++) s += Wprod1[k * 64 + c] * wro1[c];
            g_wpro[k] = s;
        }
    }
}

// prefix sum of degrees padded up to multiples of 8
__global__ __launch_bounds__(1024) void k_scan() {
    __shared__ int part[1024];
    int t = threadIdx.x;
    const int CH = (Nn + 1023) / 1024;  // 10
    int st = t * CH;
    int en = st + CH; if (en > Nn) en = Nn;
    int s = 0;
    for (int i = st; i < en; i++) s += (g_deg[i] + 7) & ~7;
    part[t] = s;
    __syncthreads();
    for (int d = 1; d < 1024; d <<= 1) {
        int v = (t >= d) ? part[t - d] : 0;
        __syncthreads();
        part[t] += v;
        __syncthreads();
    }
    int base = (t == 0) ? 0 : part[t - 1];
    for (int i = st; i < en; i++) { g_offs[i] = base; base += (g_deg[i] + 7) & ~7; }
    if (t == 1023) g_offs[Nn] = part[1023];
}

// fill slot records: pack (sender, receiver) so k_edge needs no eidx gather
__global__ __launch_bounds__(256) void k_fill(const int* __restrict__ eidx) {
    int e = blockIdx.x * 256 + threadIdx.x;
    if (e >= Ee) return;
    int snd = eidx[e];
    int r = eidx[Ee + e];
    int p = g_offs[r] + atomicAdd(&g_cursor[r], 1);
    g_er[p] = make_int2(snd, r);
}

// 2 threads per slot (32 output channels each): ~24 waves/CU of latency hiding,
// no LDS, direct float4 stores (8 insts fill a contiguous 8KB span per wave).
// Pad slots (snd<0) write zero sh; their R rows are garbage-finite (x sh=0).
__global__ __launch_bounds__(256) void k_edge(const float* __restrict__ pos,
                                              const float* __restrict__ br1,
                                              const float* __restrict__ Wr2) {
    int total = g_offs[Nn];
    if (blockIdx.x * 128 >= total) return;
    int gid = blockIdx.x * 256 + threadIdx.x;
    int s = gid >> 1;
    int half = gid & 1;
    int2 er = g_er[s];
    bool real = (er.x >= 0);
    int snd = real ? er.x : 0;
    int rcv = real ? er.y : 0;

    float vx = pos[3 * rcv + 0] - pos[3 * snd + 0];
    float vy = pos[3 * rcv + 1] - pos[3 * snd + 1];
    float vz = pos[3 * rcv + 2] - pos[3 * snd + 2];
    float r = sqrtf(vx * vx + vy * vy + vz * vz);
    float inv = __builtin_amdgcn_rcpf(fmaxf(r, 1e-9f));
    float x = vx * inv, y = vy * inv, z = vz * inv;
    const float s3 = 1.7320508f;
    if (half == 0) {
        float4* shp = (float4*)(g_shc + (size_t)s * 12);
        if (real) {
            shp[0] = make_float4(1.0f, x, y, z);
            shp[1] = make_float4(s3 * x * y, s3 * y * z, 0.5f * (3.0f * z * z - 1.0f), s3 * x * z);
            shp[2] = make_float4(0.5f * s3 * (x * x - y * y), __int_as_float(snd), 0.f, 0.f);
        } else {
            shp[0] = make_float4(0.f, 0.f, 0.f, 0.f);
            shp[1] = make_float4(0.f, 0.f, 0.f, 0.f);
            shp[2] = make_float4(0.f, 0.f, 0.f, 0.f);
        }
    }

    float xx = r * 0.2f;
    float env = 0.0f;
    if (xx < 1.0f) {
        float x2 = xx * xx;
        float x6 = x2 * x2 * x2;
        float x7 = x6 * xx;
        float x8 = x7 * xx;
        env = 1.0f - 28.0f * x6 + 48.0f * x7 - 21.0f * x8;
    }
    const float pref = 0.63245553f;  // sqrt(2/R_MAX)
    const float PI_F = 3.14159265358979f;
    float fac = pref * inv * env;
    float ef[NBb];
#pragma unroll
    for (int k = 0; k < NBb; k++)
        ef[k] = fac * __sinf((float)(k + 1) * PI_F * r * 0.2f);

    float4 acc[8];
#pragma unroll
    for (int c = 0; c < 8; c++) acc[c] = make_float4(0.f, 0.f, 0.f, 0.f);
    const float* __restrict__ w2h = Wr2 + half * 32;
    for (int j = 0; j < 64; j++) {
        float a = br1[j];
#pragma unroll
        for (int k = 0; k < NBb; k++) a += ef[k] * g_W1T[j * NBb + k];
        a = a * __builtin_amdgcn_rcpf(1.0f + __expf(-a));
        const float* __restrict__ w2 = w2h + j * 64;
#pragma unroll
        for (int c = 0; c < 8; c++) {
            acc[c].x += a * w2[4 * c + 0];
            acc[c].y += a * w2[4 * c + 1];
            acc[c].z += a * w2[4 * c + 2];
            acc[c].w += a * w2[4 * c + 3];
        }
    }
    float* dst = g_R + (size_t)s * 64 + half * 32;
#pragma unroll
    for (int c = 0; c < 8; c++) *(float4*)(dst + 4 * c) = acc[c];
}

__global__ __launch_bounds__(256) void k_hinit(const float* __restrict__ W_embed,
                                               const int* __restrict__ atom_types) {
    int i = blockIdx.x * 256 + threadIdx.x;
    if (i >= Nn * 64) return;
    int n = i >> 6, c = i & 63;
    g_h[0][i] = W_embed[atom_types[n] * 64 + c];
}

__global__ __launch_bounds__(256) void k_lin(const float* __restrict__ Wup,
                                             const float* __restrict__ Wsc, int l) {
    int t = threadIdx.x;
    int node = blockIdx.x * 4 + (t >> 6);
    int lane = t & 63;
    const float* hin = g_h[l & 1];
    float hv = hin[node * 64 + lane];
    float a1 = 0.0f, a2 = 0.0f;
#pragma unroll
    for (int k = 0; k < 64; k++) {
        float hk = __shfl(hv, k, 64);
        a1 += hk * Wup[k * 64 + lane];
        a2 += hk * Wsc[k * 64 + lane];
    }
    g_h1[node * 64 + lane] = a1;
    g_hsc[node * 64 + lane] = a2;
}

// One wave per 8-slot batch: coalesced record read, shfl unpack, 8 independent
// R + h1 loads, 72 FMAs, write per-batch partial. No atomics, no serial chains.
__global__ __launch_bounds__(256) void k_gather(int l) {
    int gid = blockIdx.x * 256 + threadIdx.x;
    int b = gid >> 6;
    int lane = gid & 63;
    int total = g_offs[Nn];
    if (b * 8 >= total) return;
    size_t j0 = (size_t)b * 8;
    float4 rec = make_float4(0.f, 0.f, 0.f, 0.f);
    if (lane < 24) rec = *(const float4*)(g_shc + j0 * 12 + (size_t)lane * 4);
    float Aa[9];
#pragma unroll
    for (int m = 0; m < 9; m++) Aa[m] = 0.0f;
#pragma unroll
    for (int k = 0; k < 8; k++) {
        float s0 = __shfl(rec.x, 3 * k, 64), s1 = __shfl(rec.y, 3 * k, 64);
        float s2 = __shfl(rec.z, 3 * k, 64), s3 = __shfl(rec.w, 3 * k, 64);
        float s4 = __shfl(rec.x, 3 * k + 1, 64), s5 = __shfl(rec.y, 3 * k + 1, 64);
        float s6 = __shfl(rec.z, 3 * k + 1, 64), s7 = __shfl(rec.w, 3 * k + 1, 64);
        float s8 = __shfl(rec.x, 3 * k + 2, 64);
        int src = __float_as_int(__shfl(rec.y, 3 * k + 2, 64));
        float rv = g_R[(j0 + k) * 64 + lane];
        float hv = g_h1[(size_t)src * 64 + lane];
        float tv = rv * hv;
        Aa[0] += s0 * tv; Aa[1] += s1 * tv; Aa[2] += s2 * tv;
        Aa[3] += s3 * tv; Aa[4] += s4 * tv; Aa[5] += s5 * tv;
        Aa[6] += s6 * tv; Aa[7] += s7 * tv; Aa[8] += s8 * tv;
    }
    float* P = g_P + (size_t)b * 576;
#pragma unroll
    for (int m = 0; m < 9; m++) P[m * 64 + lane] = Aa[m];
}

// Layer-0 finish: full h update; node energy to plain store (NO atomics).
__global__ __launch_bounds__(256) void k_finish0(const float* __restrict__ Wprod,
                                                 const float* __restrict__ wro) {
    __shared__ float sP[4096];
    int t = threadIdx.x;
    for (int i = t; i < 4096; i += 256) sP[i] = Wprod[i];
    __syncthreads();
    int node = blockIdx.x * 4 + (t >> 6);
    int lane = t & 63;
    int b0 = __builtin_amdgcn_readfirstlane(g_offs[node]) >> 3;
    int nb = (__builtin_amdgcn_readfirstlane(g_deg[node]) + 7) >> 3;
    float A[9];
#pragma unroll
    for (int m = 0; m < 9; m++) A[m] = 0.0f;
    for (int b = 0; b < nb; b++) {
        const float* P = g_P + (size_t)(b0 + b) * 576;
#pragma unroll
        for (int m = 0; m < 9; m++) A[m] += P[m * 64 + lane];
    }
    const float invn = 1.0f / 16.0f;  // AVG_NEI
    float q = A[0] * invn;
#pragma unroll
    for (int m = 0; m < 9; m++) {
        float a = A[m] * invn;
        q += a * a;
    }
    float hn = g_hsc[node * 64 + lane];
#pragma unroll
    for (int k = 0; k < 64; k++) {
        float qk = __shfl(q, k, 64);
        hn += qk * sP[k * 64 + lane];
    }
    g_h[1][node * 64 + lane] = hn;
    float v = hn * wro[lane];
#pragma unroll
    for (int off = 32; off > 0; off >>= 1) v += __shfl_down(v, off, 64);
    if (lane == 0) g_nodeE[0][node] = v;
}

// Layer-1 finish: node_e = q.(Wprod@wro) + hsc.wro — no matvec, no h store.
__global__ __launch_bounds__(256) void k_finish1(const float* __restrict__ wro) {
    int t = threadIdx.x;
    int node = blockIdx.x * 4 + (t >> 6);
    int lane = t & 63;
    int b0 = __builtin_amdgcn_readfirstlane(g_offs[node]) >> 3;
    int nb = (__builtin_amdgcn_readfirstlane(g_deg[node]) + 7) >> 3;
    float A[9];
#pragma unroll
    for (int m = 0; m < 9; m++) A[m] = 0.0f;
    for (int b = 0; b < nb; b++) {
        const float* P = g_P + (size_t)(b0 + b) * 576;
#pragma unroll
        for (int m = 0; m < 9; m++) A[m] += P[m * 64 + lane];
    }
    const float invn = 1.0f / 16.0f;  // AVG_NEI
    float q = A[0] * invn;
#pragma unroll
    for (int m = 0; m < 9; m++) {
        float a = A[m] * invn;
        q += a * a;
    }
    float v = q * g_wpro[lane] + g_hsc[node * 64 + lane] * wro[lane];
#pragma unroll
    for (int off = 32; off > 0; off >>= 1) v += __shfl_down(v, off, 64);
    if (lane == 0) g_nodeE[1][node] = v;
}

// One wave per graph; batch is sorted -> binary-search the node range,
// coalesced reduce, single plain store. Zero atomics.
__global__ __launch_bounds__(64) void k_energy(const int* __restrict__ batch,
                                               float* __restrict__ out) {
    int g = blockIdx.x;
    int lane = threadIdx.x;
    int a = 0, b = Nn;
    while (a < b) { int m = (a + b) >> 1; if (batch[m] < g) a = m + 1; else b = m; }
    int st = a;
    b = Nn;
    while (a < b) { int m = (a + b) >> 1; if (batch[m] < g + 1) a = m + 1; else b = m; }
    int en = a;
    float s = 0.0f;
    for (int i = st + lane; i < en; i += 64) s += g_nodeE[0][i] + g_nodeE[1][i];
#pragma unroll
    for (int off = 32; off > 0; off >>= 1) s += __shfl_down(s, off, 64);
    if (lane == 0) out[g] = s;
}

extern "C" void kernel_launch(void* const* d_in, const int* in_sizes, int n_in,
                              void* d_out, int out_size, void* d_ws, size_t ws_size,
                              hipStream_t stream) {
    const float* pos     = (const float*)d_in[0];
    const float* W_embed = (const float*)d_in[1];
    const float* W_r1    = (const float*)d_in[2];
    const float* b_r1    = (const float*)d_in[3];
    const float* W_r2    = (const float*)d_in[4];
    const float* W_up    = (const float*)d_in[5];
    const float* W_sc    = (const float*)d_in[6];
    const float* W_prod  = (const float*)d_in[7];
    const float* w_ro    = (const float*)d_in[8];
    const int* atom_types = (const int*)d_in[9];
    const int* eidx       = (const int*)d_in[10];
    const int* batch      = (const int*)d_in[11];
    float* out = (float*)d_out;

    k_zero<<<CSRMAX / 256, 256, 0, stream>>>(out, out_size);
    k_deg<<<Ee / 256, 256, 0, stream>>>(eidx, W_r1, W_prod + 4096, w_ro + 64);
    k_scan<<<1, 1024, 0, stream>>>();
    k_fill<<<Ee / 256, 256, 0, stream>>>(eidx);
    k_edge<<<(CSRMAX * 2) / 256, 256, 0, stream>>>(pos, b_r1, W_r2);
    k_hinit<<<(Nn * 64) / 256, 256, 0, stream>>>(W_embed, atom_types);

    k_lin<<<Nn / 4, 256, 0, stream>>>(W_up, W_sc, 0);
    k_gather<<<NBATCH / 4, 256, 0, stream>>>(0);
    k_finish0<<<Nn / 4, 256, 0, stream>>>(W_prod, w_ro);

    k_lin<<<Nn / 4, 256, 0, stream>>>(W_up + 4096, W_sc + 4096, 1);
    k_gather<<<NBATCH / 4, 256, 0, stream>>>(1);
    k_finish1<<<Nn / 4, 256, 0, stream>>>(w_ro + 64);

    k_energy<<<Gg, 64, 0, stream>>>(batch, out);
}

// Round 12
// 276.199 us; speedup vs baseline: 1.5014x; 1.5014x over previous
//
#include <hip/hip_runtime.h>
#include <math.h>

#define Nn 10000
#define Ee 160000
#define NBb 8
#define Gg 100
#define CSRMAX 230400            // >= Ee + 7*Nn, multiple of 256
#define NBATCH (CSRMAX / 8)      // 28800

// sh record per slot: [0..3]=sh0..3, [4..7]=sh4..7, [8]=sh8, [9]=src bits, [10,11]=0
__device__ __align__(16) float g_shc[(size_t)CSRMAX * 12];
__device__ __align__(16) float g_R[(size_t)CSRMAX * 64];    // [slot][64]
__device__ __align__(16) float g_P[(size_t)NBATCH * 576];   // per-batch partial A [9][64]
__device__ float g_h[2][Nn * 64];
__device__ float g_h1[Nn * 64];
__device__ float g_hsc[Nn * 64];
__device__ float g_nodeE[2][Nn];   // per-layer node energies (no atomics)
__device__ float g_wpro[64];       // W_prod[1] @ w_ro[1]
__device__ int   g_deg[Nn];
__device__ int   g_offs[Nn + 1];
__device__ int   g_cursor[Nn];
__device__ int2  g_er[CSRMAX];     // per-slot (sender, receiver); .x=-1 for pads
__device__ float g_W1T[64 * NBb];  // W_r1 transposed: [j][k]

__global__ __launch_bounds__(256) void k_zero(float* out, int out_size) {
    int i = blockIdx.x * 256 + threadIdx.x;
    if (i < CSRMAX) g_er[i].x = -1;
    if (i < out_size) out[i] = 0.0f;
    if (i < Nn) { g_deg[i] = 0; g_cursor[i] = 0; }
}

// degree count; block 0 also transposes W_r1 and computes W_prod[1]@w_ro[1]
__global__ __launch_bounds__(256) void k_deg(const int* __restrict__ eidx,
                                             const float* __restrict__ Wr1,
                                             const float* __restrict__ Wprod1,
                                             const float* __restrict__ wro1) {
    int e = blockIdx.x * 256 + threadIdx.x;
    if (e < Ee) atomicAdd(&g_deg[eidx[Ee + e]], 1);
    if (blockIdx.x == 0) {
        for (int i = threadIdx.x; i < 64 * NBb; i += 256) {
            int k = i >> 6, j = i & 63;  // Wr1[k][j]
            g_W1T[j * NBb + k] = Wr1[i];
        }
        if (threadIdx.x < 64) {
            int k = threadIdx.x;
            float s = 0.0f;
#pragma unroll
            for (int c = 0; c < 64; c++) s += Wprod1[k * 64 + c] * wro1[c];
            g_wpro[k] = s;
        }
    }
}

// prefix sum of degrees padded up to multiples of 8
__global__ __launch_bounds__(1024) void k_scan() {
    __shared__ int part[1024];
    int t = threadIdx.x;
    const int CH = (Nn + 1023) / 1024;  // 10
    int st = t * CH;
    int en = st + CH; if (en > Nn) en = Nn;
    int s = 0;
    for (int i = st; i < en; i++) s += (g_deg[i] + 7) & ~7;
    part[t] = s;
    __syncthreads();
    for (int d = 1; d < 1024; d <<= 1) {
        int v = (t >= d) ? part[t - d] : 0;
        __syncthreads();
        part[t] += v;
        __syncthreads();
    }
    int base = (t == 0) ? 0 : part[t - 1];
    for (int i = st; i < en; i++) { g_offs[i] = base; base += (g_deg[i] + 7) & ~7; }
    if (t == 1023) g_offs[Nn] = part[1023];
}

// fill slot records: pack (sender, receiver) so k_edge needs no eidx gather
__global__ __launch_bounds__(256) void k_fill(const int* __restrict__ eidx) {
    int e = blockIdx.x * 256 + threadIdx.x;
    if (e >= Ee) return;
    int snd = eidx[e];
    int r = eidx[Ee + e];
    int p = g_offs[r] + atomicAdd(&g_cursor[r], 1);
    g_er[p] = make_int2(snd, r);
}

// Thread-per-slot MLP, WAVE-UNIFORM weight reads (scalar path — do not break
// uniformity: that was the 194us regression in r11). R stores via the 32-row
// LDS transpose (0 bank conflicts measured). Blocks past the used range
// early-return; pad slots write zero sh (R rows garbage-finite, x sh=0).
__global__ __launch_bounds__(256) void k_edge(const float* __restrict__ pos,
                                              const float* __restrict__ br1,
                                              const float* __restrict__ Wr2) {
    __shared__ float sT[32][257];
    int t = threadIdx.x;
    int total = g_offs[Nn];
    if (blockIdx.x * 256 >= total) return;
    int s = blockIdx.x * 256 + t;
    int2 er = g_er[s];
    bool real = (er.x >= 0);
    int snd = real ? er.x : 0;
    int rcv = real ? er.y : 0;
    float4* shp = (float4*)(g_shc + (size_t)s * 12);

    float vx = pos[3 * rcv + 0] - pos[3 * snd + 0];
    float vy = pos[3 * rcv + 1] - pos[3 * snd + 1];
    float vz = pos[3 * rcv + 2] - pos[3 * snd + 2];
    float r = sqrtf(vx * vx + vy * vy + vz * vz);
    float inv = __builtin_amdgcn_rcpf(fmaxf(r, 1e-9f));
    float x = vx * inv, y = vy * inv, z = vz * inv;
    const float s3 = 1.7320508f;
    if (real) {
        shp[0] = make_float4(1.0f, x, y, z);
        shp[1] = make_float4(s3 * x * y, s3 * y * z, 0.5f * (3.0f * z * z - 1.0f), s3 * x * z);
        shp[2] = make_float4(0.5f * s3 * (x * x - y * y), __int_as_float(snd), 0.f, 0.f);
    } else {
        shp[0] = make_float4(0.f, 0.f, 0.f, 0.f);
        shp[1] = make_float4(0.f, 0.f, 0.f, 0.f);
        shp[2] = make_float4(0.f, 0.f, 0.f, 0.f);
    }

    float xx = r * 0.2f;
    float env = 0.0f;
    if (xx < 1.0f) {
        float x2 = xx * xx;
        float x6 = x2 * x2 * x2;
        float x7 = x6 * xx;
        float x8 = x7 * xx;
        env = 1.0f - 28.0f * x6 + 48.0f * x7 - 21.0f * x8;
    }
    const float pref = 0.63245553f;  // sqrt(2/R_MAX)
    const float PI_F = 3.14159265358979f;
    float fac = pref * inv * env;
    float ef[NBb];
#pragma unroll
    for (int k = 0; k < NBb; k++)
        ef[k] = fac * __sinf((float)(k + 1) * PI_F * r * 0.2f);

    float acc[64];
#pragma unroll
    for (int c = 0; c < 64; c++) acc[c] = 0.0f;
    for (int j = 0; j < 64; j++) {
        float a = br1[j];
#pragma unroll
        for (int k = 0; k < NBb; k++) a += ef[k] * g_W1T[j * NBb + k];
        a = a * __builtin_amdgcn_rcpf(1.0f + __expf(-a));
        const float* __restrict__ w2 = Wr2 + j * 64;
#pragma unroll
        for (int c = 0; c < 64; c++) acc[c] += a * w2[c];
    }

    size_t base = (size_t)blockIdx.x * 256;
#pragma unroll
    for (int chunk = 0; chunk < 2; chunk++) {
        int c0 = chunk * 32;
#pragma unroll
        for (int c = 0; c < 32; c++) sT[c][t] = real ? acc[c0 + c] : 0.0f;
        __syncthreads();
#pragma unroll
        for (int it = 0; it < 8; it++) {
            int idx = it * 256 + t;
            int ss = idx >> 3, c4 = idx & 7;
            float4 v = make_float4(sT[c4 * 4 + 0][ss], sT[c4 * 4 + 1][ss],
                                   sT[c4 * 4 + 2][ss], sT[c4 * 4 + 3][ss]);
            *(float4*)(g_R + (base + ss) * 64 + c0 + c4 * 4) = v;
        }
        __syncthreads();
    }
}

__global__ __launch_bounds__(256) void k_hinit(const float* __restrict__ W_embed,
                                               const int* __restrict__ atom_types) {
    int i = blockIdx.x * 256 + threadIdx.x;
    if (i >= Nn * 64) return;
    int n = i >> 6, c = i & 63;
    g_h[0][i] = W_embed[atom_types[n] * 64 + c];
}

__global__ __launch_bounds__(256) void k_lin(const float* __restrict__ Wup,
                                             const float* __restrict__ Wsc, int l) {
    int t = threadIdx.x;
    int node = blockIdx.x * 4 + (t >> 6);
    int lane = t & 63;
    const float* hin = g_h[l & 1];
    float hv = hin[node * 64 + lane];
    float a1 = 0.0f, a2 = 0.0f;
#pragma unroll
    for (int k = 0; k < 64; k++) {
        float hk = __shfl(hv, k, 64);
        a1 += hk * Wup[k * 64 + lane];
        a2 += hk * Wsc[k * 64 + lane];
    }
    g_h1[node * 64 + lane] = a1;
    g_hsc[node * 64 + lane] = a2;
}

// One wave per 8-slot batch: coalesced record read, shfl unpack, 8 independent
// R + h1 loads, 72 FMAs, write per-batch partial. No atomics, no serial chains.
__global__ __launch_bounds__(256) void k_gather(int l) {
    int gid = blockIdx.x * 256 + threadIdx.x;
    int b = gid >> 6;
    int lane = gid & 63;
    int total = g_offs[Nn];
    if (b * 8 >= total) return;
    size_t j0 = (size_t)b * 8;
    float4 rec = make_float4(0.f, 0.f, 0.f, 0.f);
    if (lane < 24) rec = *(const float4*)(g_shc + j0 * 12 + (size_t)lane * 4);
    float Aa[9];
#pragma unroll
    for (int m = 0; m < 9; m++) Aa[m] = 0.0f;
#pragma unroll
    for (int k = 0; k < 8; k++) {
        float s0 = __shfl(rec.x, 3 * k, 64), s1 = __shfl(rec.y, 3 * k, 64);
        float s2 = __shfl(rec.z, 3 * k, 64), s3 = __shfl(rec.w, 3 * k, 64);
        float s4 = __shfl(rec.x, 3 * k + 1, 64), s5 = __shfl(rec.y, 3 * k + 1, 64);
        float s6 = __shfl(rec.z, 3 * k + 1, 64), s7 = __shfl(rec.w, 3 * k + 1, 64);
        float s8 = __shfl(rec.x, 3 * k + 2, 64);
        int src = __float_as_int(__shfl(rec.y, 3 * k + 2, 64));
        float rv = g_R[(j0 + k) * 64 + lane];
        float hv = g_h1[(size_t)src * 64 + lane];
        float tv = rv * hv;
        Aa[0] += s0 * tv; Aa[1] += s1 * tv; Aa[2] += s2 * tv;
        Aa[3] += s3 * tv; Aa[4] += s4 * tv; Aa[5] += s5 * tv;
        Aa[6] += s6 * tv; Aa[7] += s7 * tv; Aa[8] += s8 * tv;
    }
    float* P = g_P + (size_t)b * 576;
#pragma unroll
    for (int m = 0; m < 9; m++) P[m * 64 + lane] = Aa[m];
}

// Layer-0 finish: full h update; node energy to plain store (NO atomics).
__global__ __launch_bounds__(256) void k_finish0(const float* __restrict__ Wprod,
                                                 const float* __restrict__ wro) {
    __shared__ float sP[4096];
    int t = threadIdx.x;
    for (int i = t; i < 4096; i += 256) sP[i] = Wprod[i];
    __syncthreads();
    int node = blockIdx.x * 4 + (t >> 6);
    int lane = t & 63;
    int b0 = __builtin_amdgcn_readfirstlane(g_offs[node]) >> 3;
    int nb = (__builtin_amdgcn_readfirstlane(g_deg[node]) + 7) >> 3;
    float A[9];
#pragma unroll
    for (int m = 0; m < 9; m++) A[m] = 0.0f;
    for (int b = 0; b < nb; b++) {
        const float* P = g_P + (size_t)(b0 + b) * 576;
#pragma unroll
        for (int m = 0; m < 9; m++) A[m] += P[m * 64 + lane];
    }
    const float invn = 1.0f / 16.0f;  // AVG_NEI
    float q = A[0] * invn;
#pragma unroll
    for (int m = 0; m < 9; m++) {
        float a = A[m] * invn;
        q += a * a;
    }
    float hn = g_hsc[node * 64 + lane];
#pragma unroll
    for (int k = 0; k < 64; k++) {
        float qk = __shfl(q, k, 64);
        hn += qk * sP[k * 64 + lane];
    }
    g_h[1][node * 64 + lane] = hn;
    float v = hn * wro[lane];
#pragma unroll
    for (int off = 32; off > 0; off >>= 1) v += __shfl_down(v, off, 64);
    if (lane == 0) g_nodeE[0][node] = v;
}

// Layer-1 finish: node_e = q.(Wprod@wro) + hsc.wro — no matvec, no h store.
__global__ __launch_bounds__(256) void k_finish1(const float* __restrict__ wro) {
    int t = threadIdx.x;
    int node = blockIdx.x * 4 + (t >> 6);
    int lane = t & 63;
    int b0 = __builtin_amdgcn_readfirstlane(g_offs[node]) >> 3;
    int nb = (__builtin_amdgcn_readfirstlane(g_deg[node]) + 7) >> 3;
    float A[9];
#pragma unroll
    for (int m = 0; m < 9; m++) A[m] = 0.0f;
    for (int b = 0; b < nb; b++) {
        const float* P = g_P + (size_t)(b0 + b) * 576;
#pragma unroll
        for (int m = 0; m < 9; m++) A[m] += P[m * 64 + lane];
    }
    const float invn = 1.0f / 16.0f;  // AVG_NEI
    float q = A[0] * invn;
#pragma unroll
    for (int m = 0; m < 9; m++) {
        float a = A[m] * invn;
        q += a * a;
    }
    float v = q * g_wpro[lane] + g_hsc[node * 64 + lane] * wro[lane];
#pragma unroll
    for (int off = 32; off > 0; off >>= 1) v += __shfl_down(v, off, 64);
    if (lane == 0) g_nodeE[1][node] = v;
}

// One wave per graph; batch is sorted -> binary-search the node range,
// coalesced reduce, single plain store. Zero atomics.
__global__ __launch_bounds__(64) void k_energy(const int* __restrict__ batch,
                                               float* __restrict__ out) {
    int g = blockIdx.x;
    int lane = threadIdx.x;
    int a = 0, b = Nn;
    while (a < b) { int m = (a + b) >> 1; if (batch[m] < g) a = m + 1; else b = m; }
    int st = a;
    b = Nn;
    while (a < b) { int m = (a + b) >> 1; if (batch[m] < g + 1) a = m + 1; else b = m; }
    int en = a;
    float s = 0.0f;
    for (int i = st + lane; i < en; i += 64) s += g_nodeE[0][i] + g_nodeE[1][i];
#pragma unroll
    for (int off = 32; off > 0; off >>= 1) s += __shfl_down(s, off, 64);
    if (lane == 0) out[g] = s;
}

extern "C" void kernel_launch(void* const* d_in, const int* in_sizes, int n_in,
                              void* d_out, int out_size, void* d_ws, size_t ws_size,
                              hipStream_t stream) {
    const float* pos     = (const float*)d_in[0];
    const float* W_embed = (const float*)d_in[1];
    const float* W_r1    = (const float*)d_in[2];
    const float* b_r1    = (const float*)d_in[3];
    const float* W_r2    = (const float*)d_in[4];
    const float* W_up    = (const float*)d_in[5];
    const float* W_sc    = (const float*)d_in[6];
    const float* W_prod  = (const float*)d_in[7];
    const float* w_ro    = (const float*)d_in[8];
    const int* atom_types = (const int*)d_in[9];
    const int* eidx       = (const int*)d_in[10];
    const int* batch      = (const int*)d_in[11];
    float* out = (float*)d_out;

    k_zero<<<CSRMAX / 256, 256, 0, stream>>>(out, out_size);
    k_deg<<<Ee / 256, 256, 0, stream>>>(eidx, W_r1, W_prod + 4096, w_ro + 64);
    k_scan<<<1, 1024, 0, stream>>>();
    k_fill<<<Ee / 256, 256, 0, stream>>>(eidx);
    k_edge<<<CSRMAX / 256, 256, 0, stream>>>(pos, b_r1, W_r2);
    k_hinit<<<(Nn * 64) / 256, 256, 0, stream>>>(W_embed, atom_types);

    k_lin<<<Nn / 4, 256, 0, stream>>>(W_up, W_sc, 0);
    k_gather<<<NBATCH / 4, 256, 0, stream>>>(0);
    k_finish0<<<Nn / 4, 256, 0, stream>>>(W_prod, w_ro);

    k_lin<<<Nn / 4, 256, 0, stream>>>(W_up + 4096, W_sc + 4096, 1);
    k_gather<<<NBATCH / 4, 256, 0, stream>>>(1);
    k_finish1<<<Nn / 4, 256, 0, stream>>>(w_ro + 64);

    k_energy<<<Gg, 64, 0, stream>>>(batch, out);
}